// Round 3
// baseline (745.512 us; speedup 1.0000x reference)
//
#include <hip/hip_runtime.h>
#include <cstdint>
#include <cstddef>

// Problem constants
#define T_TOKENS 4096
#define DM 1024
#define DF 4096
#define NE 8
#define TOPK 2
#define BK 32
#define MAX_MT 72   // max sum over experts of ceil(count_e/128); worst case 71
#define MSLOTS 8192 // TOPK * T_TOKENS

typedef short short8 __attribute__((ext_vector_type(8)));
typedef float f32x4 __attribute__((ext_vector_type(4)));

__device__ __forceinline__ unsigned short f2h_bits(float f) {
  _Float16 h = (_Float16)f;   // RNE
  union { _Float16 h; unsigned short u; } v; v.h = h; return v.u;
}

typedef __attribute__((address_space(3))) void lds_void_t;
typedef __attribute__((address_space(1))) void gvoid_t;
__device__ __forceinline__ void gl_lds16(const void* g, void* l) {
  __builtin_amdgcn_global_load_lds((gvoid_t*)g, (lds_void_t*)l, 16, 0, 0);
}

// ------------- gate: fp32 logits, top-2, softmax, histogram; also emit Xh fp16 -------------
__global__ void gate_kernel(const float* __restrict__ x, const float* __restrict__ Wg,
                            int* __restrict__ sel, float* __restrict__ wts,
                            int* __restrict__ counts, unsigned short* __restrict__ Xh) {
  int wave = threadIdx.x >> 6, lane = threadIdx.x & 63;
  int t = blockIdx.x * 4 + wave;
  const float* xr = x + (size_t)t * DM;
  unsigned short* xh = Xh + (size_t)t * DM;
  float acc[NE];
#pragma unroll
  for (int e = 0; e < NE; e++) acc[e] = 0.f;
#pragma unroll
  for (int j = 0; j < 4; j++) {
    int d4 = (lane + 64 * j) * 4;
    float4 v = *(const float4*)(xr + d4);
    ushort4 o;
    o.x = f2h_bits(v.x); o.y = f2h_bits(v.y); o.z = f2h_bits(v.z); o.w = f2h_bits(v.w);
    *(ushort4*)(xh + d4) = o;
    const float* wr = Wg + (size_t)d4 * NE;
#pragma unroll
    for (int e = 0; e < NE; e++) acc[e] += v.x * wr[e];
#pragma unroll
    for (int e = 0; e < NE; e++) acc[e] += v.y * wr[NE + e];
#pragma unroll
    for (int e = 0; e < NE; e++) acc[e] += v.z * wr[2 * NE + e];
#pragma unroll
    for (int e = 0; e < NE; e++) acc[e] += v.w * wr[3 * NE + e];
  }
#pragma unroll
  for (int e = 0; e < NE; e++) {
    float v = acc[e];
#pragma unroll
    for (int off = 32; off > 0; off >>= 1) v += __shfl_down(v, off, 64);
    acc[e] = v;
  }
  if (lane == 0) {
    int b0 = 0;
#pragma unroll
    for (int e = 1; e < NE; e++) if (acc[e] > acc[b0]) b0 = e;   // first-index tie-break
    int b1 = (b0 == 0) ? 1 : 0;
#pragma unroll
    for (int e = 0; e < NE; e++) if (e != b0 && acc[e] > acc[b1]) b1 = e;
    float p = expf(acc[b1] - acc[b0]);
    float w0 = 1.f / (1.f + p);
    sel[t * 2] = b0; sel[t * 2 + 1] = b1;
    wts[t * 2] = w0; wts[t * 2 + 1] = p * w0;
    atomicAdd(&counts[b0], 1);
    atomicAdd(&counts[b1], 1);
  }
}

// ---------------- scan: offsets, gemm tile offsets, cursors ----------------
__global__ void scan_kernel(const int* __restrict__ counts, int* __restrict__ offsets,
                            int* __restrict__ tile_off, int* __restrict__ cursors) {
  if (threadIdx.x == 0) {
    int o = 0, to = 0;
    offsets[0] = 0; tile_off[0] = 0;
    for (int e = 0; e < NE; e++) {
      cursors[e] = o;
      o += counts[e];
      to += (counts[e] + 127) >> 7;
      offsets[e + 1] = o;
      tile_off[e + 1] = to;
    }
  }
}

// ---------------- scatter: token -> compacted slot lists + inverse map ----------------
__global__ void scatter_kernel(const int* __restrict__ sel, const float* __restrict__ wts,
                               int* __restrict__ cursors, int* __restrict__ rows,
                               float* __restrict__ rw, int* __restrict__ inv) {
  int t = blockIdx.x * 256 + threadIdx.x;
  if (t >= T_TOKENS) return;
#pragma unroll
  for (int k = 0; k < TOPK; k++) {
    int e = sel[t * 2 + k];
    int slot = atomicAdd(&cursors[e], 1);
    rows[slot] = t;
    rw[slot] = wts[t * 2 + k];
    inv[t * 2 + k] = slot;
  }
}

// ------- fp32 -> fp16 transpose (per expert): out[c][r] = in[r][c], 64x64 tiles -------
// fp32 LDS tile, stride 65 (65 mod 32 == 1 -> both phases exactly 2-way bank aliasing = free)
__global__ void transpose_convert(const float* __restrict__ in, unsigned short* __restrict__ outp,
                                  int R, int C) {
  __shared__ float tile[64 * 65];
  const float* inE = in + (size_t)blockIdx.z * R * C;
  unsigned short* outE = outp + (size_t)blockIdx.z * R * C;
  int c0 = blockIdx.x * 64, r0 = blockIdx.y * 64;
  int tid = threadIdx.x;
  int rr = tid >> 4, c4 = (tid & 15) * 4;
#pragma unroll
  for (int it = 0; it < 4; it++) {
    int r = rr + 16 * it;
    float4 v = *(const float4*)(inE + (size_t)(r0 + r) * C + c0 + c4);
    tile[r * 65 + c4 + 0] = v.x;
    tile[r * 65 + c4 + 1] = v.y;
    tile[r * 65 + c4 + 2] = v.z;
    tile[r * 65 + c4 + 3] = v.w;
  }
  __syncthreads();
#pragma unroll
  for (int it = 0; it < 2; it++) {
    int idx = tid + 256 * it;           // 512 ushort8 units: c = idx>>3, r8 = (idx&7)*8
    int c = idx >> 3, r8 = (idx & 7) * 8;
    short8 val;
#pragma unroll
    for (int j = 0; j < 8; j++) val[j] = (short)f2h_bits(tile[(r8 + j) * 65 + c]);
    *(short8*)(outE + (size_t)(c0 + c) * R + r0 + r8) = val;
  }
}

// ---------------- grouped GEMM (m97 structure): C = A(MxK) * Bt(NxK)^T ----------------
// SECOND=false (INDIR=true):  H = relu(Xh[rows]*W1t^T + b1), fp16, LDS-staged coalesced stores
// SECOND=true  (INDIR=false): split-K=2; S[ks][slot] = rw[slot]*(H*W2t^T partial + b2*(ks==0))
template <int K, int N, bool INDIR, bool SECOND, int KSPLIT>
__global__ __launch_bounds__(256, 2) void moe_gemm(
    const unsigned short* __restrict__ Aall, const unsigned short* __restrict__ Ball,
    unsigned short* __restrict__ Hout, float* __restrict__ Sout,
    const float* __restrict__ bias, const int* __restrict__ counts,
    const int* __restrict__ offsets, const int* __restrict__ tile_off,
    const int* __restrict__ rows, const float* __restrict__ rw) {
  __shared__ __align__(16) unsigned short lds[8704];   // 4096 A + 4096 B; epilogue reuses 64x136
  unsigned short* ldsA = lds;
  unsigned short* ldsB = lds + 4096;

  int bx = blockIdx.x;
  int e = 0;
#pragma unroll 1
  while (e < NE && bx >= tile_off[e + 1]) e++;
  if (e >= NE) return;
  int lt = bx - tile_off[e];
  int cnt = counts[e];
  int m0 = lt * 128;
  int rowbase = offsets[e];
  int nt = blockIdx.y % (N / 128);
  int ks = blockIdx.y / (N / 128);
  int n0 = nt * 128;
  int k0 = ks * (K / KSPLIT);

  const unsigned short* Be = Ball + ((size_t)e * N + n0) * K;

  int tid = threadIdx.x;
  int lane = tid & 63, wave = tid >> 6;
  int wm = wave & 1, wn = wave >> 1;

  // staging: idx in [0,512), row = idx>>2, seg = idx&3, each lane moves 16B
  int rA0 = tid >> 2, rA1 = (256 + tid) >> 2, seg = tid & 3;
  int mA0 = m0 + rA0; if (mA0 >= cnt) mA0 = cnt - 1;
  int mA1 = m0 + rA1; if (mA1 >= cnt) mA1 = cnt - 1;
  size_t ia0 = INDIR ? (size_t)rows[rowbase + mA0] : (size_t)(rowbase + mA0);
  size_t ia1 = INDIR ? (size_t)rows[rowbase + mA1] : (size_t)(rowbase + mA1);
  const unsigned short* srcA0 = Aall + ia0 * K + seg * 8;
  const unsigned short* srcA1 = Aall + ia1 * K + seg * 8;
  const unsigned short* srcB0 = Be + (size_t)rA0 * K + seg * 8;
  const unsigned short* srcB1 = Be + (size_t)rA1 * K + seg * 8;
  unsigned short* dA0 = ldsA + (size_t)tid * 8;
  unsigned short* dA1 = ldsA + (size_t)(256 + tid) * 8;
  unsigned short* dB0 = ldsB + (size_t)tid * 8;
  unsigned short* dB1 = ldsB + (size_t)(256 + tid) * 8;

  f32x4 acc[4][4] = {};

  for (int kk = k0; kk < k0 + K / KSPLIT; kk += BK) {
    gl_lds16(srcA0 + kk, dA0);
    gl_lds16(srcA1 + kk, dA1);
    gl_lds16(srcB0 + kk, dB0);
    gl_lds16(srcB1 + kk, dB1);
    __syncthreads();

    short8 af[4], bfr[4];
#pragma unroll
    for (int t4 = 0; t4 < 4; t4++) {
      af[t4]  = *(const short8*)(ldsA + (wm * 64 + t4 * 16 + (lane & 15)) * BK + (lane >> 4) * 8);
      bfr[t4] = *(const short8*)(ldsB + (wn * 64 + t4 * 16 + (lane & 15)) * BK + (lane >> 4) * 8);
    }
#pragma unroll
    for (int tm = 0; tm < 4; tm++)
#pragma unroll
      for (int tn = 0; tn < 4; tn++)
        acc[tm][tn] = __builtin_amdgcn_mfma_f32_16x16x32_f16(af[tm], bfr[tn], acc[tm][tn], 0, 0, 0);
    __syncthreads();
  }

  // epilogue: C/D layout col=lane&15, row=(lane>>4)*4+reg
  int quad = lane >> 4, c16 = lane & 15;
  if constexpr (!SECOND) {
    // stage 64 rows at a time in LDS (fp16, stride 136), then coalesced short8 stores
#pragma unroll 1
    for (int half = 0; half < 2; half++) {
      __syncthreads();
      if (wm == half) {
#pragma unroll
        for (int tm = 0; tm < 4; tm++) {
#pragma unroll
          for (int tn = 0; tn < 4; tn++) {
            int colL = wn * 64 + tn * 16 + c16;
            float b = bias[e * N + n0 + colL];
#pragma unroll
            for (int r = 0; r < 4; r++) {
              int rl = tm * 16 + quad * 4 + r;   // 0..63
              float v = fmaxf(acc[tm][tn][r] + b, 0.f);
              lds[rl * 136 + colL] = f2h_bits(v);
            }
          }
        }
      }
      __syncthreads();
#pragma unroll
      for (int i = 0; i < 4; i++) {
        int idx = tid + 256 * i;                 // 1024 ushort8 units
        int row = idx >> 4, c8 = (idx & 15) * 8;
        int grow = m0 + half * 64 + row;
        if (grow < cnt) {
          short8 val = *(const short8*)(lds + row * 136 + c8);
          *(short8*)(Hout + (size_t)(rowbase + grow) * N + n0 + c8) = val;
        }
      }
    }
  } else {
    float* Sk = Sout + (size_t)ks * MSLOTS * N;
#pragma unroll
    for (int tm = 0; tm < 4; tm++) {
#pragma unroll
      for (int tn = 0; tn < 4; tn++) {
        int gcol = n0 + wn * 64 + tn * 16 + c16;
        float b = (ks == 0) ? bias[e * N + gcol] : 0.f;
#pragma unroll
        for (int r = 0; r < 4; r++) {
          int rl = wm * 64 + tm * 16 + quad * 4 + r;
          if (m0 + rl < cnt) {
            int slot = rowbase + m0 + rl;
            Sk[(size_t)slot * N + gcol] = (acc[tm][tn][r] + b) * rw[slot];
          }
        }
      }
    }
  }
}

// ------- combine: out[t] = S0[inv0]+S1[inv0]+S0[inv1]+S1[inv1] (rw already folded) -------
__global__ void combine_kernel(const float* __restrict__ S, const int* __restrict__ inv,
                               float* __restrict__ out) {
  int wave = threadIdx.x >> 6, lane = threadIdx.x & 63;
  int t = blockIdx.x * 4 + wave;
  int s0 = inv[t * 2], s1 = inv[t * 2 + 1];
  const float4* a0 = (const float4*)(S + (size_t)s0 * DM);
  const float4* a1 = (const float4*)(S + (size_t)(MSLOTS + s0) * DM);
  const float4* b0 = (const float4*)(S + (size_t)s1 * DM);
  const float4* b1 = (const float4*)(S + (size_t)(MSLOTS + s1) * DM);
  float4* o = (float4*)(out + (size_t)t * DM);
#pragma unroll
  for (int j = 0; j < 4; j++) {
    int i = lane + 64 * j;
    float4 va = a0[i], vb = a1[i], vc = b0[i], vd = b1[i];
    float4 vo;
    vo.x = (va.x + vb.x) + (vc.x + vd.x);
    vo.y = (va.y + vb.y) + (vc.y + vd.y);
    vo.z = (va.z + vb.z) + (vc.z + vd.z);
    vo.w = (va.w + vb.w) + (vc.w + vd.w);
    o[i] = vo;
  }
}

extern "C" void kernel_launch(void* const* d_in, const int* in_sizes, int n_in,
                              void* d_out, int out_size, void* d_ws, size_t ws_size,
                              hipStream_t stream) {
  const float* x  = (const float*)d_in[0];
  const float* Wg = (const float*)d_in[1];
  const float* W1 = (const float*)d_in[2];
  const float* b1 = (const float*)d_in[3];
  const float* W2 = (const float*)d_in[4];
  const float* b2 = (const float*)d_in[5];
  float* out = (float*)d_out;

  char* ws = (char*)d_ws;
  int*   counts   = (int*)(ws + 0);
  int*   cursors  = (int*)(ws + 64);
  int*   offsets  = (int*)(ws + 128);
  int*   tile_off = (int*)(ws + 192);
  int*   sel      = (int*)(ws + 256);                  // 32 KB
  float* wts      = (float*)(ws + 33024);              // 32 KB
  int*   rows     = (int*)(ws + 65792);                // 32 KB
  float* rw       = (float*)(ws + 98560);              // 32 KB
  int*   inv      = (int*)(ws + 131328);               // 32 KB
  unsigned short* Xh  = (unsigned short*)(ws + 164096);                    // 8.39 MB
  unsigned short* H   = (unsigned short*)(ws + 8552704);                   // 67.1 MB
  unsigned short* W1t = (unsigned short*)(ws + 75661568);                  // 67.1 MB
  float*          S   = (float*)(ws + 75661568);                           // aliases W1t (dead after GEMM1); S0|S1 = 2x33.55 MB
  unsigned short* W2t = (unsigned short*)(ws + 142770432);                 // 67.1 MB; end = 209.9 MB

  hipMemsetAsync(ws, 0, 128, stream);   // counts + cursors

  gate_kernel<<<T_TOKENS / 4, 256, 0, stream>>>(x, Wg, sel, wts, counts, Xh);
  scan_kernel<<<1, 64, 0, stream>>>(counts, offsets, tile_off, cursors);
  scatter_kernel<<<T_TOKENS / 256, 256, 0, stream>>>(sel, wts, cursors, rows, rw, inv);
  // W1 (E, D, F) -> W1t (E, F, D);  W2 (E, F, D) -> W2t (E, D, F)
  transpose_convert<<<dim3(DF / 64, DM / 64, NE), 256, 0, stream>>>(W1, W1t, DM, DF);
  transpose_convert<<<dim3(DM / 64, DF / 64, NE), 256, 0, stream>>>(W2, W2t, DF, DM);

  moe_gemm<DM, DF, true, false, 1><<<dim3(MAX_MT, DF / 128), 256, 0, stream>>>(
      Xh, W1t, H, nullptr, b1, counts, offsets, tile_off, rows, rw);
  moe_gemm<DF, DM, false, true, 2><<<dim3(MAX_MT, (DM / 128) * 2), 256, 0, stream>>>(
      H, W2t, nullptr, S, b2, counts, offsets, tile_off, rows, rw);

  combine_kernel<<<T_TOKENS / 4, 256, 0, stream>>>(S, inv, out);
}

// Round 4
// 688.313 us; speedup vs baseline: 1.0831x; 1.0831x over previous
//
#include <hip/hip_runtime.h>
#include <cstdint>
#include <cstddef>

// Problem constants
#define T_TOKENS 4096
#define DM 1024
#define DF 4096
#define NE 8
#define TOPK 2
#define BK 32
#define MAX_MT 72   // max sum over experts of ceil(count_e/128); worst case 71
#define MSLOTS 8192 // TOPK * T_TOKENS

typedef short short8 __attribute__((ext_vector_type(8)));
typedef float f32x4 __attribute__((ext_vector_type(4)));

__device__ __forceinline__ unsigned short f2h_bits(float f) {
  _Float16 h = (_Float16)f;   // RNE
  union { _Float16 h; unsigned short u; } v; v.h = h; return v.u;
}

typedef __attribute__((address_space(3))) void lds_void_t;
typedef __attribute__((address_space(1))) void gvoid_t;
__device__ __forceinline__ void gl_lds16(const void* g, void* l) {
  __builtin_amdgcn_global_load_lds((gvoid_t*)g, (lds_void_t*)l, 16, 0, 0);
}

// ------------- gate: fp32 logits, top-2, softmax, histogram; also emit Xh fp16 -------------
__global__ void gate_kernel(const float* __restrict__ x, const float* __restrict__ Wg,
                            int* __restrict__ sel, float* __restrict__ wts,
                            int* __restrict__ counts, unsigned short* __restrict__ Xh) {
  int wave = threadIdx.x >> 6, lane = threadIdx.x & 63;
  int t = blockIdx.x * 4 + wave;
  const float* xr = x + (size_t)t * DM;
  unsigned short* xh = Xh + (size_t)t * DM;
  float acc[NE];
#pragma unroll
  for (int e = 0; e < NE; e++) acc[e] = 0.f;
#pragma unroll
  for (int j = 0; j < 4; j++) {
    int d4 = (lane + 64 * j) * 4;
    float4 v = *(const float4*)(xr + d4);
    ushort4 o;
    o.x = f2h_bits(v.x); o.y = f2h_bits(v.y); o.z = f2h_bits(v.z); o.w = f2h_bits(v.w);
    *(ushort4*)(xh + d4) = o;
    const float* wr = Wg + (size_t)d4 * NE;
#pragma unroll
    for (int e = 0; e < NE; e++) acc[e] += v.x * wr[e];
#pragma unroll
    for (int e = 0; e < NE; e++) acc[e] += v.y * wr[NE + e];
#pragma unroll
    for (int e = 0; e < NE; e++) acc[e] += v.z * wr[2 * NE + e];
#pragma unroll
    for (int e = 0; e < NE; e++) acc[e] += v.w * wr[3 * NE + e];
  }
#pragma unroll
  for (int e = 0; e < NE; e++) {
    float v = acc[e];
#pragma unroll
    for (int off = 32; off > 0; off >>= 1) v += __shfl_down(v, off, 64);
    acc[e] = v;
  }
  if (lane == 0) {
    int b0 = 0;
#pragma unroll
    for (int e = 1; e < NE; e++) if (acc[e] > acc[b0]) b0 = e;   // first-index tie-break
    int b1 = (b0 == 0) ? 1 : 0;
#pragma unroll
    for (int e = 0; e < NE; e++) if (e != b0 && acc[e] > acc[b1]) b1 = e;
    float p = expf(acc[b1] - acc[b0]);
    float w0 = 1.f / (1.f + p);
    sel[t * 2] = b0; sel[t * 2 + 1] = b1;
    wts[t * 2] = w0; wts[t * 2 + 1] = p * w0;
    atomicAdd(&counts[b0], 1);
    atomicAdd(&counts[b1], 1);
  }
}

// ---------------- scan: offsets, gemm tile offsets, cursors ----------------
__global__ void scan_kernel(const int* __restrict__ counts, int* __restrict__ offsets,
                            int* __restrict__ tile_off, int* __restrict__ cursors) {
  if (threadIdx.x == 0) {
    int o = 0, to = 0;
    offsets[0] = 0; tile_off[0] = 0;
    for (int e = 0; e < NE; e++) {
      cursors[e] = o;
      o += counts[e];
      to += (counts[e] + 127) >> 7;
      offsets[e + 1] = o;
      tile_off[e + 1] = to;
    }
  }
}

// ---------------- scatter: token -> compacted slot lists + inverse map ----------------
__global__ void scatter_kernel(const int* __restrict__ sel, const float* __restrict__ wts,
                               int* __restrict__ cursors, int* __restrict__ rows,
                               float* __restrict__ rw, int* __restrict__ inv) {
  int t = blockIdx.x * 256 + threadIdx.x;
  if (t >= T_TOKENS) return;
#pragma unroll
  for (int k = 0; k < TOPK; k++) {
    int e = sel[t * 2 + k];
    int slot = atomicAdd(&cursors[e], 1);
    rows[slot] = t;
    rw[slot] = wts[t * 2 + k];
    inv[t * 2 + k] = slot;
  }
}

// ------- fp32 -> fp16 transpose, both weights in ONE launch -------
// blockIdx.y = z: z<8 -> W1 expert z (R=DM,C=DF); else W2 expert z-8 (R=DF,C=DM)
// fp32 LDS tile, stride 65 (65 mod 32 == 1 -> both phases exactly 2-way bank aliasing = free)
__global__ void transpose_convert(const float* __restrict__ W1, unsigned short* __restrict__ W1t,
                                  const float* __restrict__ W2, unsigned short* __restrict__ W2t) {
  __shared__ float tile[64 * 65];
  int z = blockIdx.y;
  int R, C;
  const float* inE;
  unsigned short* outE;
  int tidx = blockIdx.x;   // 1024 tiles per expert-matrix
  int bx, by;
  if (z < 8) {
    R = DM; C = DF;
    inE = W1 + (size_t)z * DM * DF;
    outE = W1t + (size_t)z * DM * DF;
    bx = tidx % (DF / 64); by = tidx / (DF / 64);
  } else {
    R = DF; C = DM;
    inE = W2 + (size_t)(z - 8) * DM * DF;
    outE = W2t + (size_t)(z - 8) * DM * DF;
    bx = tidx % (DM / 64); by = tidx / (DM / 64);
  }
  int c0 = bx * 64, r0 = by * 64;
  int tid = threadIdx.x;
  int rr = tid >> 4, c4 = (tid & 15) * 4;
#pragma unroll
  for (int it = 0; it < 4; it++) {
    int r = rr + 16 * it;
    float4 v = *(const float4*)(inE + (size_t)(r0 + r) * C + c0 + c4);
    tile[r * 65 + c4 + 0] = v.x;
    tile[r * 65 + c4 + 1] = v.y;
    tile[r * 65 + c4 + 2] = v.z;
    tile[r * 65 + c4 + 3] = v.w;
  }
  __syncthreads();
#pragma unroll
  for (int it = 0; it < 2; it++) {
    int idx = tid + 256 * it;           // 512 ushort8 units: c = idx>>3, r8 = (idx&7)*8
    int c = idx >> 3, r8 = (idx & 7) * 8;
    short8 val;
#pragma unroll
    for (int j = 0; j < 8; j++) val[j] = (short)f2h_bits(tile[(r8 + j) * 65 + c]);
    *(short8*)(outE + (size_t)(c0 + c) * R + r0 + r8) = val;
  }
}

// ---------------- grouped GEMM (m97 structure): C = A(MxK) * Bt(NxK)^T ----------------
// 1-D grid, XCD-aware: n_tile = id % NT (id%8 ~ XCD -> B panel pinned per-XCD L2),
//                      m_tile = id / NT (all XCDs pull same A tile together -> L3 hit)
// SECOND=false (INDIR=true):  H = relu(Xh[rows]*W1t^T + b1), fp16, LDS-staged coalesced stores
// SECOND=true  (INDIR=false): S[slot] = rw[slot]*(H*W2t^T + b2), plain fp32 stores
template <int K, int N, int NT, bool INDIR, bool SECOND>
__global__ __launch_bounds__(256, 4) void moe_gemm(
    const unsigned short* __restrict__ Aall, const unsigned short* __restrict__ Ball,
    unsigned short* __restrict__ Hout, float* __restrict__ Sout,
    const float* __restrict__ bias, const int* __restrict__ counts,
    const int* __restrict__ offsets, const int* __restrict__ tile_off,
    const int* __restrict__ rows, const float* __restrict__ rw) {
  __shared__ __align__(16) unsigned short lds[8704];   // 4096 A + 4096 B; epilogue reuses 64x136
  unsigned short* ldsA = lds;
  unsigned short* ldsB = lds + 4096;

  int id = blockIdx.x;
  int nt = id % NT;
  int bx = id / NT;
  int e = 0;
#pragma unroll 1
  while (e < NE && bx >= tile_off[e + 1]) e++;
  if (e >= NE) return;
  int lt = bx - tile_off[e];
  int cnt = counts[e];
  int m0 = lt * 128;
  int rowbase = offsets[e];
  int n0 = nt * 128;

  const unsigned short* Be = Ball + ((size_t)e * N + n0) * K;

  int tid = threadIdx.x;
  int lane = tid & 63, wave = tid >> 6;
  int wm = wave & 1, wn = wave >> 1;

  // staging: idx in [0,512), row = idx>>2, seg = idx&3, each lane moves 16B
  int rA0 = tid >> 2, rA1 = (256 + tid) >> 2, seg = tid & 3;
  int mA0 = m0 + rA0; if (mA0 >= cnt) mA0 = cnt - 1;
  int mA1 = m0 + rA1; if (mA1 >= cnt) mA1 = cnt - 1;
  size_t ia0 = INDIR ? (size_t)rows[rowbase + mA0] : (size_t)(rowbase + mA0);
  size_t ia1 = INDIR ? (size_t)rows[rowbase + mA1] : (size_t)(rowbase + mA1);
  const unsigned short* srcA0 = Aall + ia0 * K + seg * 8;
  const unsigned short* srcA1 = Aall + ia1 * K + seg * 8;
  const unsigned short* srcB0 = Be + (size_t)rA0 * K + seg * 8;
  const unsigned short* srcB1 = Be + (size_t)rA1 * K + seg * 8;
  unsigned short* dA0 = ldsA + (size_t)tid * 8;
  unsigned short* dA1 = ldsA + (size_t)(256 + tid) * 8;
  unsigned short* dB0 = ldsB + (size_t)tid * 8;
  unsigned short* dB1 = ldsB + (size_t)(256 + tid) * 8;

  f32x4 acc[4][4] = {};

  for (int kk = 0; kk < K; kk += BK) {
    gl_lds16(srcA0 + kk, dA0);
    gl_lds16(srcA1 + kk, dA1);
    gl_lds16(srcB0 + kk, dB0);
    gl_lds16(srcB1 + kk, dB1);
    __syncthreads();

    short8 af[4], bfr[4];
#pragma unroll
    for (int t4 = 0; t4 < 4; t4++) {
      af[t4]  = *(const short8*)(ldsA + (wm * 64 + t4 * 16 + (lane & 15)) * BK + (lane >> 4) * 8);
      bfr[t4] = *(const short8*)(ldsB + (wn * 64 + t4 * 16 + (lane & 15)) * BK + (lane >> 4) * 8);
    }
#pragma unroll
    for (int tm = 0; tm < 4; tm++)
#pragma unroll
      for (int tn = 0; tn < 4; tn++)
        acc[tm][tn] = __builtin_amdgcn_mfma_f32_16x16x32_f16(af[tm], bfr[tn], acc[tm][tn], 0, 0, 0);
    __syncthreads();
  }

  // epilogue: C/D layout col=lane&15, row=(lane>>4)*4+reg
  int quad = lane >> 4, c16 = lane & 15;
  if constexpr (!SECOND) {
    // stage 64 rows at a time in LDS (fp16, stride 136), then coalesced short8 stores
#pragma unroll 1
    for (int half = 0; half < 2; half++) {
      __syncthreads();
      if (wm == half) {
#pragma unroll
        for (int tm = 0; tm < 4; tm++) {
#pragma unroll
          for (int tn = 0; tn < 4; tn++) {
            int colL = wn * 64 + tn * 16 + c16;
            float b = bias[e * N + n0 + colL];
#pragma unroll
            for (int r = 0; r < 4; r++) {
              int rl = tm * 16 + quad * 4 + r;   // 0..63
              float v = fmaxf(acc[tm][tn][r] + b, 0.f);
              lds[rl * 136 + colL] = f2h_bits(v);
            }
          }
        }
      }
      __syncthreads();
#pragma unroll
      for (int i = 0; i < 4; i++) {
        int idx = tid + 256 * i;                 // 1024 ushort8 units
        int row = idx >> 4, c8 = (idx & 15) * 8;
        int grow = m0 + half * 64 + row;
        if (grow < cnt) {
          short8 val = *(const short8*)(lds + row * 136 + c8);
          *(short8*)(Hout + (size_t)(rowbase + grow) * N + n0 + c8) = val;
        }
      }
    }
  } else {
#pragma unroll
    for (int tm = 0; tm < 4; tm++) {
#pragma unroll
      for (int tn = 0; tn < 4; tn++) {
        int gcol = n0 + wn * 64 + tn * 16 + c16;
        float b = bias[e * N + gcol];
#pragma unroll
        for (int r = 0; r < 4; r++) {
          int rl = wm * 64 + tm * 16 + quad * 4 + r;
          if (m0 + rl < cnt) {
            int slot = rowbase + m0 + rl;
            Sout[(size_t)slot * N + gcol] = (acc[tm][tn][r] + b) * rw[slot];
          }
        }
      }
    }
  }
}

// ---------------- combine: out[t] = S[inv0] + S[inv1]  (rw already folded) ----------------
__global__ void combine_kernel(const float* __restrict__ S, const int* __restrict__ inv,
                               float* __restrict__ out) {
  int wave = threadIdx.x >> 6, lane = threadIdx.x & 63;
  int t = blockIdx.x * 4 + wave;
  int s0 = inv[t * 2], s1 = inv[t * 2 + 1];
  const float4* a = (const float4*)(S + (size_t)s0 * DM);
  const float4* b = (const float4*)(S + (size_t)s1 * DM);
  float4* o = (float4*)(out + (size_t)t * DM);
#pragma unroll
  for (int j = 0; j < 4; j++) {
    float4 va = a[lane + 64 * j], vb = b[lane + 64 * j];
    float4 vo; vo.x = va.x + vb.x; vo.y = va.y + vb.y; vo.z = va.z + vb.z; vo.w = va.w + vb.w;
    o[lane + 64 * j] = vo;
  }
}

extern "C" void kernel_launch(void* const* d_in, const int* in_sizes, int n_in,
                              void* d_out, int out_size, void* d_ws, size_t ws_size,
                              hipStream_t stream) {
  const float* x  = (const float*)d_in[0];
  const float* Wg = (const float*)d_in[1];
  const float* W1 = (const float*)d_in[2];
  const float* b1 = (const float*)d_in[3];
  const float* W2 = (const float*)d_in[4];
  const float* b2 = (const float*)d_in[5];
  float* out = (float*)d_out;

  char* ws = (char*)d_ws;
  int*   counts   = (int*)(ws + 0);
  int*   cursors  = (int*)(ws + 64);
  int*   offsets  = (int*)(ws + 128);
  int*   tile_off = (int*)(ws + 192);
  int*   sel      = (int*)(ws + 256);                  // 32 KB
  float* wts      = (float*)(ws + 33024);              // 32 KB
  int*   rows     = (int*)(ws + 65792);                // 32 KB
  float* rw       = (float*)(ws + 98560);              // 32 KB
  int*   inv      = (int*)(ws + 131328);               // 32 KB
  unsigned short* Xh  = (unsigned short*)(ws + 164096);                    // 8.39 MB
  unsigned short* H   = (unsigned short*)(ws + 8552704);                   // 67.1 MB
  unsigned short* W1t = (unsigned short*)(ws + 75661568);                  // 67.1 MB
  float*          S   = (float*)(ws + 75661568);                           // aliases W1t (dead after GEMM1)
  unsigned short* W2t = (unsigned short*)(ws + 142770432);                 // 67.1 MB; end = 209.9 MB

  hipMemsetAsync(ws, 0, 128, stream);   // counts + cursors

  gate_kernel<<<T_TOKENS / 4, 256, 0, stream>>>(x, Wg, sel, wts, counts, Xh);
  scan_kernel<<<1, 64, 0, stream>>>(counts, offsets, tile_off, cursors);
  scatter_kernel<<<T_TOKENS / 256, 256, 0, stream>>>(sel, wts, cursors, rows, rw, inv);
  // W1 (E, D, F) -> W1t (E, F, D);  W2 (E, F, D) -> W2t (E, D, F), single launch
  transpose_convert<<<dim3(1024, 16), 256, 0, stream>>>(W1, W1t, W2, W2t);

  moe_gemm<DM, DF, 32, true, false><<<MAX_MT * 32, 256, 0, stream>>>(
      Xh, W1t, H, nullptr, b1, counts, offsets, tile_off, rows, rw);
  moe_gemm<DF, DM, 8, false, true><<<MAX_MT * 8, 256, 0, stream>>>(
      H, W2t, nullptr, S, b2, counts, offsets, tile_off, rows, rw);

  combine_kernel<<<T_TOKENS / 4, 256, 0, stream>>>(S, inv, out);
}